// Round 15
// baseline (4415.720 us; speedup 1.0000x reference)
//
#include <hip/hip_runtime.h>

#define B_ 64
#define S_ 256
#define F_ 256
#define H_ 1024

typedef __attribute__((ext_vector_type(8))) short bf16x8;
typedef __attribute__((ext_vector_type(4))) float f32x4;
typedef unsigned long long u64;

#define MFMA(a, b, c) __builtin_amdgcn_mfma_f32_16x16x32_bf16(a, b, c, 0, 0, 0)
#define CBAR() asm volatile("" ::: "memory")

__device__ __forceinline__ float sig(float v) { return 1.0f / (1.0f + __expf(-v)); }
__device__ __forceinline__ float tanh_(float v) { return 1.0f - 2.0f / (__expf(2.0f * v) + 1.0f); }
__device__ __forceinline__ short bfr(float f) {  // fp32 -> bf16 RNE
    unsigned u = __float_as_uint(f);
    u += 0x7fffu + ((u >> 16) & 1u);
    return (short)(u >> 16);
}

// agent-scope write-through 4B store (visible at coherence point)
__device__ __forceinline__ void st4(short* base, size_t byteoff, unsigned v) {
    __hip_atomic_store((unsigned*)((char*)base + byteoff), v,
                       __ATOMIC_RELAXED, __HIP_MEMORY_SCOPE_AGENT);
}

// early arrival: wave drains own stores, LDS pair-counter; 2nd of pair bumps the line.
__device__ __forceinline__ void arrive2(unsigned* cnt_lds, unsigned* line, int lane, unsigned step) {
    asm volatile("s_waitcnt vmcnt(0)" ::: "memory");
    if (lane == 0) {
        unsigned old = __hip_atomic_fetch_add(cnt_lds, 1u, __ATOMIC_RELAXED,
                                              __HIP_MEMORY_SCOPE_WORKGROUP);
        if (old == 2u * step + 1u)
            __hip_atomic_fetch_add(line, 1u, __ATOMIC_RELAXED, __HIP_MEMORY_SCOPE_AGENT);
    }
}

// master-only: parallel poll of 32 counter lines
__device__ __forceinline__ void flag_wait_g(unsigned* lines, int lane31, unsigned tgt) {
    for (;;) {
        unsigned s = __hip_atomic_load(&lines[lane31 * 16], __ATOMIC_RELAXED,
                                       __HIP_MEMORY_SCOPE_AGENT);
        s += __shfl_xor(s, 1);
        s += __shfl_xor(s, 2);
        s += __shfl_xor(s, 4);
        s += __shfl_xor(s, 8);
        s += __shfl_xor(s, 16);
        if (s >= tgt) break;
        __builtin_amdgcn_s_sleep(1);
    }
    CBAR();
}

__device__ __forceinline__ void master_release(unsigned* lines, unsigned* rel,
                                               int lane, int lane31,
                                               unsigned tgt, unsigned val) {
    flag_wait_g(lines, lane31, tgt);
    if (lane < 8)
        __hip_atomic_store(&rel[lane * 16], val, __ATOMIC_RELAXED, __HIP_MEMORY_SCOPE_AGENT);
}

// non-master: single release-line poll
__device__ __forceinline__ void rel_wait(unsigned* f, unsigned tgt) {
    while (__hip_atomic_load(f, __ATOMIC_RELAXED, __HIP_MEMORY_SCOPE_AGENT) < tgt)
        __builtin_amdgcn_s_sleep(1);
    CBAR();
}

__device__ __forceinline__ void tok_spin(volatile unsigned* tk, unsigned v) {
    while (*tk < v) __builtin_amdgcn_s_sleep(1);
    CBAR();
}

// x pre-conversion into A-frag layout: [t][kf 8][m 4][lane 64][8]
__global__ __launch_bounds__(256) void conv_x(const float* __restrict__ x,
                                              short* __restrict__ xbf) {
    int tid = blockIdx.x * 256 + threadIdx.x;
    int lane = tid & 63;
    int m = (tid >> 6) & 3;
    int kf = (tid >> 8) & 7;
    int t = tid >> 11;
    int b = m * 16 + (lane & 15);
    int kb = kf * 32 + (lane >> 4) * 8;
    const float* src = x + ((size_t)b * S_ + t) * F_ + kb;
    float4 v0 = *(const float4*)src, v1 = *(const float4*)(src + 4);
    bf16x8 o;
    o[0] = bfr(v0.x); o[1] = bfr(v0.y); o[2] = bfr(v0.z); o[3] = bfr(v0.w);
    o[4] = bfr(v1.x); o[5] = bfr(v1.y); o[6] = bfr(v1.z); o[7] = bfr(v1.w);
    *(bf16x8*)(xbf + (size_t)tid * 8) = o;
}

__global__ void zero_f(float* __restrict__ p, int n) {
    int i = blockIdx.x * blockDim.x + threadIdx.x;
    if (i < n) p[i] = 0.0f;
}

// one-time: M = Wa * fcW into B-frag layout; c0 = Wa * fcb
__global__ __launch_bounds__(256) void precomp(const float* __restrict__ Wih0,
                                               const float* __restrict__ fcW,
                                               const float* __restrict__ fcb,
                                               short* __restrict__ Mf,
                                               float* __restrict__ c0ws) {
    __shared__ float WaL[16][256];
    const int nf = blockIdx.x, tid = threadIdx.x;
    #pragma unroll
    for (int r = 0; r < 16; ++r) {
        int rowp = nf * 16 + r;
        int up = rowp >> 2, gat = rowp & 3;
        WaL[r][tid] = Wih0[(size_t)(gat * H_ + up) * 512 + 256 + tid];
    }
    __syncthreads();
    f32x4 acc[16];
    #pragma unroll
    for (int r = 0; r < 16; ++r) acc[r] = (f32x4){0, 0, 0, 0};
    for (int c = 0; c < 256; ++c) {
        f32x4 wv = *(const f32x4*)&fcW[(size_t)c * 1024 + tid * 4];
        #pragma unroll
        for (int r = 0; r < 16; ++r) acc[r] += WaL[r][c] * wv;
    }
    #pragma unroll
    for (int r = 0; r < 16; ++r) {
        #pragma unroll
        for (int jj = 0; jj < 4; ++jj) {
            int h = tid * 4 + jj;
            int kf = h >> 5;
            int lane = r + ((h >> 3) & 3) * 16;
            int j = h & 7;
            Mf[((size_t)nf * 32 + kf) * 512 + lane * 8 + j] = bfr(acc[r][jj]);
        }
    }
    if (tid < 16) {
        float s = 0.0f;
        for (int c = 0; c < 256; ++c) s += WaL[tid][c] * fcb[c];
        c0ws[nf * 16 + tid] = s;
    }
}

#define GATES(v)                                                        \
    float x1 = __shfl_xor((v), 1), x2 = __shfl_xor((v), 2), x3 = __shfl_xor((v), 3); \
    float aL = g1 ? x1 : (v), aH = g1 ? x3 : x2;                        \
    float bL = g1 ? (v) : x1, bH = g1 ? x2 : x3;                        \
    float i_ = g2 ? aH : aL;                                            \
    float f_ = g2 ? bH : bL;                                            \
    float gc = g2 ? aL : aH;                                            \
    float o_ = g2 ? bL : bH;                                            \
    i_ = sig(i_); f_ = sig(f_); o_ = sig(o_); gc = tanh_(gc);

__global__ __launch_bounds__(512, 1) void persist(
    const float* __restrict__ Wih0, const float* __restrict__ Whh0,
    const float* __restrict__ bih0, const float* __restrict__ bhh0,
    const float* __restrict__ Wih1, const float* __restrict__ Whh1,
    const float* __restrict__ bih1, const float* __restrict__ bhh1,
    const float* __restrict__ fcW,  const float* __restrict__ fcb,
    const float* __restrict__ x,    const short* __restrict__ xbf,
    short* __restrict__ h0S, short* __restrict__ h1S,
    const short* __restrict__ Mf, const float* __restrict__ c0ws,
    float* __restrict__ outp,
    unsigned* __restrict__ flagAlo, unsigned* __restrict__ flagAhi,
    unsigned* __restrict__ flagBlo, unsigned* __restrict__ flagBhi,
    unsigned* __restrict__ relAlo,  unsigned* __restrict__ relAhi,
    unsigned* __restrict__ relBlo,  unsigned* __restrict__ relBhi)
{
    __shared__ f32x4 redGA[2048];   // 32 KB  ga partials
    __shared__ f32x4 redBv[2048];   // 32 KB  layer1 partials
    __shared__ f32x4 redDv[2048];   // 32 KB  P-update partials
    __shared__ f32x4 fcF[256];      //  4 KB  fc partials
    __shared__ short ldsC[16384];   // 32 KB  fc weights (nf<64)
    __shared__ unsigned tokAlo, tokAhi, tokBlo, tokBhi;
    __shared__ unsigned cA[2], cB[2];
    const int tid = threadIdx.x, lane = tid & 63, w = tid >> 6;   // w 0..7
    const int nf = blockIdx.x;
    const int lane31 = lane & 31;
    unsigned* lineAlo = &flagAlo[(nf >> 3) * 16];
    unsigned* lineAhi = &flagAhi[(nf >> 3) * 16];
    unsigned* lineBlo = &flagBlo[(nf >> 3) * 16];
    unsigned* lineBhi = &flagBhi[(nf >> 3) * 16];
    unsigned* myRelAlo = &relAlo[(nf >> 5) * 16];
    unsigned* myRelAhi = &relAhi[(nf >> 5) * 16];
    unsigned* myRelBlo = &relBlo[(nf >> 5) * 16];
    unsigned* myRelBhi = &relBhi[(nf >> 5) * 16];
    const int rowp = nf * 16 + (lane & 15);
    const int up = rowp >> 2, g = rowp & 3;
    const int g1 = lane & 1, g2 = lane & 2;
    const f32x4 zero4 = {0, 0, 0, 0};
    const int chunkA = (nf >> 3) * 4 + w;         // (w<4)
    const int lsBase = ((nf & 7) >> 1) * 16;
    const int pb = (nf & 1) * 4 + ((lane & 15) >> 3) * 2;
    const int mfc = nf >> 4;

    if (tid == 0) {
        tokAlo = 0; tokAhi = 0; tokBlo = 0; tokBhi = 0;
        cA[0] = 0; cA[1] = 0; cB[0] = 0; cB[1] = 0;
    }

    // ---- prologue: weights -> registers (role-specialized) ----
    bf16x8 wA0, waQ, wH[8], wX[8];
    {
        int k = w * 32 + (lane >> 4) * 8;
        const float* src = Wih0 + (size_t)(g * H_ + up) * 512 + k;
        #pragma unroll
        for (int j = 0; j < 8; ++j) wA0[j] = bfr(src[j]);
    }
    {
        int k = 256 + w * 32 + (lane >> 4) * 8;
        const float* src = Wih0 + (size_t)(g * H_ + up) * 512 + k;
        #pragma unroll
        for (int j = 0; j < 8; ++j) waQ[j] = bfr(src[j]);
    }
    if (w < 4) {
        #pragma unroll
        for (int i = 0; i < 8; ++i) {
            int k = (w * 8 + i) * 32 + (lane >> 4) * 8;
            const float* sh = Whh0 + (size_t)(g * H_ + up) * 1024 + k;
            const float* sx = Wih1 + (size_t)(g * H_ + up) * 1024 + k;
            #pragma unroll
            for (int j = 0; j < 8; ++j) { wH[i][j] = bfr(sh[j]); wX[i][j] = bfr(sx[j]); }
        }
    } else {
        #pragma unroll
        for (int i = 0; i < 8; ++i) {
            int k = ((w - 4) * 8 + i) * 32 + (lane >> 4) * 8;
            const float* sh = Whh1 + (size_t)(g * H_ + up) * 1024 + k;
            #pragma unroll
            for (int j = 0; j < 8; ++j) wH[i][j] = bfr(sh[j]);
            wX[i] = *(const bf16x8*)(Mf + ((size_t)nf * 32 + (w - 4) * 8 + i) * 512 + lane * 8);
        }
    }
    const float bias0 = bih0[g * H_ + up] + bhh0[g * H_ + up];
    const float bias1 = bih1[g * H_ + up] + bhh1[g * H_ + up];
    const float c0l = c0ws[nf * 16 + (lane & 15)];
    float biasC = 0.0f;
    if (nf < 64) {
        int rowc = (nf & 15) * 16 + (lane & 15);
        biasC = fcb[rowc];
        #pragma unroll
        for (int i = 0; i < 4; ++i) {
            int kf = w * 4 + i;
            int k = kf * 32 + (lane >> 4) * 8;
            const float* src = fcW + (size_t)rowc * 1024 + k;
            short* d = ldsC + ((size_t)kf * 64 + lane) * 8;
            #pragma unroll
            for (int j = 0; j < 8; ++j) d[j] = bfr(src[j]);
        }
    }
    __syncthreads();

    float cs0[4] = {0, 0, 0, 0}, cs1[4] = {0, 0, 0, 0};
    float areg[4] = {0, 0, 0, 0}, P[4] = {0, 0, 0, 0};

    // ---- prologue A1(0): x/Q MFMAs; h0(-1)=0 ----
    f32x4 ga0, ga1, ga2, ga3, q0, q1, q2, q3;
    f32x4 qp0 = zero4, qp1 = zero4, qp2 = zero4, qp3 = zero4;
    {
        const short* p = xbf + (size_t)w * 2048 + lane * 8;
        bf16x8 a0 = *(const bf16x8*)(p);
        bf16x8 a1 = *(const bf16x8*)(p + 512);
        bf16x8 a2 = *(const bf16x8*)(p + 1024);
        bf16x8 a3 = *(const bf16x8*)(p + 1536);
        ga0 = MFMA(a0, wA0, zero4);  ga1 = MFMA(a1, wA0, zero4);
        ga2 = MFMA(a2, wA0, zero4);  ga3 = MFMA(a3, wA0, zero4);
        q0 = MFMA(a0, waQ, zero4);  q1 = MFMA(a1, waQ, zero4);
        q2 = MFMA(a2, waQ, zero4);  q3 = MFMA(a3, waQ, zero4);
    }

    for (int t = 0; t < S_; ++t) {
        const unsigned ut = (unsigned)t;
        short* h0w = h0S + (size_t)t * 65536;            // h0(t)
        const short* h1r = h1S + (size_t)t * 65536;      // h1(t-1)
        short* h1w = h1S + (size_t)(t + 1) * 65536;      // h1(t)

        // ===== s1: hopB (lo/hi) + waves 4-7 merged hh + M pass over h1(t-1) =====
        if (w == 0 && t > 0) {
            if (nf == 0) {
                master_release(flagBlo, relBlo, lane, lane31, 256u * ut, ut);
                if (lane == 0) *(volatile unsigned*)&tokBlo = ut;
                CBAR();
                master_release(flagBhi, relBhi, lane, lane31, 256u * ut, ut);
                if (lane == 0) *(volatile unsigned*)&tokBhi = ut;
                CBAR();
            } else {
                rel_wait(myRelBlo, ut);
                if (lane == 0) *(volatile unsigned*)&tokBlo = ut;
                CBAR();
                rel_wait(myRelBhi, ut);
                if (lane == 0) *(volatile unsigned*)&tokBhi = ut;
                CBAR();
            }
        }
        redGA[(w * 4 + 0) * 64 + lane] = ga0;
        redGA[(w * 4 + 1) * 64 + lane] = ga1;
        redGA[(w * 4 + 2) * 64 + lane] = ga2;
        redGA[(w * 4 + 3) * 64 + lane] = ga3;
        f32x4 m0 = zero4, m1 = zero4, m2 = zero4, m3 = zero4;
        if (w >= 4) {
            f32x4 b0 = zero4, b1 = zero4, b2 = zero4, b3 = zero4;
            if (t > 0) tok_spin(&tokBlo, ut);
            #pragma unroll
            for (int i = 0; i < 8; ++i) {
                const short* p = h1r + (size_t)((w - 4) * 8 + i) * 2048 + lane * 8;
                bf16x8 a0 = *(const bf16x8*)(p);
                bf16x8 a1 = *(const bf16x8*)(p + 512);
                if (t > 1) {
                    m0 = MFMA(a0, wX[i], m0);
                    m1 = MFMA(a1, wX[i], m1);
                }
                b0 = MFMA(a0, wH[i], b0);
                b1 = MFMA(a1, wH[i], b1);
            }
            if (t > 0) tok_spin(&tokBhi, ut);
            #pragma unroll
            for (int i = 0; i < 8; ++i) {
                const short* p = h1r + (size_t)((w - 4) * 8 + i) * 2048 + lane * 8;
                bf16x8 a2 = *(const bf16x8*)(p + 1024);
                bf16x8 a3 = *(const bf16x8*)(p + 1536);
                if (t > 1) {
                    m2 = MFMA(a2, wX[i], m2);
                    m3 = MFMA(a3, wX[i], m3);
                }
                b2 = MFMA(a2, wH[i], b2);
                b3 = MFMA(a3, wH[i], b3);
            }
            redBv[(w * 4 + 0) * 64 + lane] = b0;
            redBv[(w * 4 + 1) * 64 + lane] = b1;
            redBv[(w * 4 + 2) * 64 + lane] = b2;
            redBv[(w * 4 + 3) * 64 + lane] = b3;
        }
        if (t > 0) {
            f32x4 R0, R1, R2, R3;
            if (t == 1) { R0 = qp0; R1 = qp1; R2 = qp2; R3 = qp3; }
            else if (w >= 4) {
                R0 = 1.15f * qp0 + 0.2f * m0;
                R1 = 1.15f * qp1 + 0.2f * m1;
                R2 = 1.15f * qp2 + 0.2f * m2;
                R3 = 1.15f * qp3 + 0.2f * m3;
            } else {
                R0 = 1.15f * qp0; R1 = 1.15f * qp1; R2 = 1.15f * qp2; R3 = 1.15f * qp3;
            }
            redDv[(w * 4 + 0) * 64 + lane] = R0;
            redDv[(w * 4 + 1) * 64 + lane] = R1;
            redDv[(w * 4 + 2) * 64 + lane] = R2;
            redDv[(w * 4 + 3) * 64 + lane] = R3;
        }
        __syncthreads();

        // ===== s2: waves 0-3: P-update + A3 pointwise + h0 publish (early arrive);
        //           waves 4-7: fc partials (out t-1) =====
        if (w < 4) {
            if (t > 0) {
                f32x4 sD = redDv[(0 * 4 + w) * 64 + lane];
                #pragma unroll
                for (int k = 1; k < 8; ++k) sD += redDv[(k * 4 + w) * 64 + lane];
                #pragma unroll
                for (int r = 0; r < 4; ++r)
                    P[r] = (t == 1) ? sD[r]
                         : (sD[r] + 0.15f * P[r] + 0.2f * c0l) * (1.0f / 1.5f);
            }
            f32x4 s = redGA[(0 * 4 + w) * 64 + lane];
            #pragma unroll
            for (int k = 1; k < 8; ++k) s += redGA[(k * 4 + w) * 64 + lane];
            #pragma unroll
            for (int r = 0; r < 4; ++r) {
                float v = s[r] + bias0 + P[r];
                GATES(v)
                float cn = f_ * cs0[r] + i_ * gc;
                cs0[r] = cn;
                float hn = o_ * tanh_(cn);
                int hv = (int)(unsigned short)bfr(hn);
                int ot = __shfl_xor(hv, 4);
                unsigned p32 = (lane & 4) ? (unsigned)((ot & 0xffff) | (hv << 16))
                                          : (unsigned)((hv & 0xffff) | (ot << 16));
                if ((lane & 7) == 0) {
                    int b = w * 16 + (lane >> 4) * 4 + r;
                    int ls = lsBase + (b & 15);
                    st4(h0w, (size_t)chunkA * 1024 + (size_t)ls * 16 + pb * 2, p32);
                }
            }
            arrive2(&cA[w >> 1], (w >> 1) ? lineAhi : lineAlo, lane, ut);
        } else if (nf < 64 && t > 0) {
            const int j = w - 4;
            f32x4 f0 = zero4;
            #pragma unroll
            for (int i = 0; i < 8; ++i) {
                const int kf = j * 8 + i;
                const bf16x8 bw = *(const bf16x8*)(ldsC + ((size_t)kf * 64 + lane) * 8);
                bf16x8 a = *(const bf16x8*)(h1r + (size_t)kf * 2048 + (size_t)mfc * 512 + lane * 8);
                f0 = MFMA(a, bw, f0);
            }
            fcF[j * 64 + lane] = f0;
        }
        __syncthreads();

        // ===== s3+s4: hopA (lo/hi) + merged ih + next-step Whh0 pass over h0(t);
        //              wave 4 blends out(t-1) in the shadow =====
        if (w == 4 && nf < 64 && t > 0) {
            f32x4 s = fcF[lane];
            s += fcF[64 + lane];
            s += fcF[128 + lane];
            s += fcF[192 + lane];
            const int c = (nf & 15) * 16 + (lane & 15);
            #pragma unroll
            for (int r = 0; r < 4; ++r) {
                float ov = s[r] + biasC;
                int b = mfc * 16 + (lane >> 4) * 4 + r;
                size_t xi = ((size_t)b * S_ + (t - 1)) * F_ + c;
                float xv = x[xi];
                float na = (t == 1) ? xv
                         : (1.15f * xv + 0.15f * areg[r] + 0.2f * ov) * (1.0f / 1.5f);
                areg[r] = na;
                outp[xi] = na;
            }
        }
        if (w == 0) {
            if (nf == 0) {
                master_release(flagAlo, relAlo, lane, lane31, 256u * (ut + 1u), ut + 1u);
                if (lane == 0) *(volatile unsigned*)&tokAlo = ut + 1u;
                CBAR();
                master_release(flagAhi, relAhi, lane, lane31, 256u * (ut + 1u), ut + 1u);
                if (lane == 0) *(volatile unsigned*)&tokAhi = ut + 1u;
                CBAR();
            } else {
                rel_wait(myRelAlo, ut + 1u);
                if (lane == 0) *(volatile unsigned*)&tokAlo = ut + 1u;
                CBAR();
            }
        }
        if (w < 4) {
            f32x4 b0 = zero4, b1 = zero4, b2 = zero4, b3 = zero4;
            if (w != 0) tok_spin(&tokAlo, ut + 1u);
            ga0 = zero4; ga1 = zero4; ga2 = zero4; ga3 = zero4;
            #pragma unroll
            for (int i = 0; i < 8; ++i) {
                const short* p = h0w + (size_t)(w * 8 + i) * 2048 + lane * 8;
                bf16x8 a0 = *(const bf16x8*)(p);
                bf16x8 a1 = *(const bf16x8*)(p + 512);
                b0 = MFMA(a0, wX[i], b0);
                b1 = MFMA(a1, wX[i], b1);
                ga0 = MFMA(a0, wH[i], ga0);
                ga1 = MFMA(a1, wH[i], ga1);
            }
            if (w == 0) {
                if (nf == 0) {
                    // hi already released above (back-to-back); nothing to do
                } else {
                    rel_wait(myRelAhi, ut + 1u);
                    if (lane == 0) *(volatile unsigned*)&tokAhi = ut + 1u;
                    CBAR();
                }
            } else {
                tok_spin(&tokAhi, ut + 1u);
            }
            #pragma unroll
            for (int i = 0; i < 8; ++i) {
                const short* p = h0w + (size_t)(w * 8 + i) * 2048 + lane * 8;
                bf16x8 a2 = *(const bf16x8*)(p + 1024);
                bf16x8 a3 = *(const bf16x8*)(p + 1536);
                b2 = MFMA(a2, wX[i], b2);
                b3 = MFMA(a3, wX[i], b3);
                ga2 = MFMA(a2, wH[i], ga2);
                ga3 = MFMA(a3, wH[i], ga3);
            }
            redBv[(w * 4 + 0) * 64 + lane] = b0;
            redBv[(w * 4 + 1) * 64 + lane] = b1;
            redBv[(w * 4 + 2) * 64 + lane] = b2;
            redBv[(w * 4 + 3) * 64 + lane] = b3;
        }
        __syncthreads();

        // ===== s5: B epilogue (waves 0-3), publish h1(t), early arrive =====
        if (w < 4) {
            f32x4 s = redBv[(0 * 4 + w) * 64 + lane];
            #pragma unroll
            for (int k = 1; k < 8; ++k) s += redBv[(k * 4 + w) * 64 + lane];
            #pragma unroll
            for (int r = 0; r < 4; ++r) {
                float v = s[r] + bias1;
                GATES(v)
                float cn = f_ * cs1[r] + i_ * gc;
                cs1[r] = cn;
                float hn = o_ * tanh_(cn);
                int hv = (int)(unsigned short)bfr(hn);
                int ot = __shfl_xor(hv, 4);
                unsigned p32 = (lane & 4) ? (unsigned)((ot & 0xffff) | (hv << 16))
                                          : (unsigned)((hv & 0xffff) | (ot << 16));
                if ((lane & 7) == 0) {
                    int b = w * 16 + (lane >> 4) * 4 + r;
                    int ls = lsBase + (b & 15);
                    st4(h1w, (size_t)chunkA * 1024 + (size_t)ls * 16 + pb * 2, p32);
                }
            }
            arrive2(&cB[w >> 1], (w >> 1) ? lineBhi : lineBlo, lane, ut);
        }
        __syncthreads();

        // ===== s6: A1(t+1) x/Q (hopB filler) =====
        if (t < S_ - 1) {
            qp0 = q0; qp1 = q1; qp2 = q2; qp3 = q3;
            const short* p = xbf + (size_t)(t + 1) * 16384 + (size_t)w * 2048 + lane * 8;
            bf16x8 a0 = *(const bf16x8*)(p);
            bf16x8 a1 = *(const bf16x8*)(p + 512);
            bf16x8 a2 = *(const bf16x8*)(p + 1024);
            bf16x8 a3 = *(const bf16x8*)(p + 1536);
            ga0 = MFMA(a0, wA0, (w < 4) ? ga0 : zero4);
            ga1 = MFMA(a1, wA0, (w < 4) ? ga1 : zero4);
            ga2 = MFMA(a2, wA0, (w < 4) ? ga2 : zero4);
            ga3 = MFMA(a3, wA0, (w < 4) ? ga3 : zero4);
            q0 = MFMA(a0, waQ, zero4);  q1 = MFMA(a1, waQ, zero4);
            q2 = MFMA(a2, waQ, zero4);  q3 = MFMA(a3, waQ, zero4);
        }
    }

    // ===== tail: out(255) from h1(255) (slot 256) =====
    if (w == 0) {
        if (nf == 0) {
            master_release(flagBlo, relBlo, lane, lane31, 256u * 256u, 256u);
            master_release(flagBhi, relBhi, lane, lane31, 256u * 256u, 256u);
        } else {
            rel_wait(myRelBlo, 256u);
            rel_wait(myRelBhi, 256u);
        }
        if (lane == 0) { *(volatile unsigned*)&tokBlo = 256u; *(volatile unsigned*)&tokBhi = 256u; }
        CBAR();
    } else if (w >= 4) {
        tok_spin(&tokBhi, 256u);
    }
    if (nf < 64) {
        const short* h1f = h1S + (size_t)256 * 65536;
        if (w >= 4) {
            const int j = w - 4;
            f32x4 f0 = zero4;
            #pragma unroll
            for (int i = 0; i < 8; ++i) {
                const int kf = j * 8 + i;
                const bf16x8 bw = *(const bf16x8*)(ldsC + ((size_t)kf * 64 + lane) * 8);
                bf16x8 a = *(const bf16x8*)(h1f + (size_t)kf * 2048 + (size_t)mfc * 512 + lane * 8);
                f0 = MFMA(a, bw, f0);
            }
            fcF[j * 64 + lane] = f0;
        }
        __syncthreads();
        if (w == 4) {
            f32x4 s = fcF[lane];
            s += fcF[64 + lane];
            s += fcF[128 + lane];
            s += fcF[192 + lane];
            const int c = (nf & 15) * 16 + (lane & 15);
            #pragma unroll
            for (int r = 0; r < 4; ++r) {
                float ov = s[r] + biasC;
                int b = mfc * 16 + (lane >> 4) * 4 + r;
                size_t xi = ((size_t)b * S_ + (S_ - 1)) * F_ + c;
                float xv = x[xi];
                float na = (1.15f * xv + 0.15f * areg[r] + 0.2f * ov) * (1.0f / 1.5f);
                outp[xi] = na;
            }
        }
    }
}

extern "C" void kernel_launch(void* const* d_in, const int* in_sizes, int n_in,
                              void* d_out, int out_size, void* d_ws, size_t ws_size,
                              hipStream_t stream) {
    const float* x    = (const float*)d_in[0];
    const float* Wih0 = (const float*)d_in[1];
    const float* Whh0 = (const float*)d_in[2];
    const float* bih0 = (const float*)d_in[3];
    const float* bhh0 = (const float*)d_in[4];
    const float* Wih1 = (const float*)d_in[5];
    const float* Whh1 = (const float*)d_in[6];
    const float* bih1 = (const float*)d_in[7];
    const float* bhh1 = (const float*)d_in[8];
    const float* fcW  = (const float*)d_in[9];
    const float* fcb  = (const float*)d_in[10];
    float* outp = (float*)d_out;

    char* ws = (char*)d_ws;
    short* xbf   = (short*)(ws + 0);                // 8,388,608 B
    short* Mf    = (short*)(ws + 8388608);          // 8,388,608 B
    float* c0ws  = (float*)(ws + 16777216);         //    16,384 B
    unsigned* flagAlo = (unsigned*)(ws + 16793600); // 2,048 B each
    unsigned* flagAhi = (unsigned*)(ws + 16795648);
    unsigned* flagBlo = (unsigned*)(ws + 16797696);
    unsigned* flagBhi = (unsigned*)(ws + 16799744);
    unsigned* relAlo  = (unsigned*)(ws + 16801792); //   512 B each
    unsigned* relAhi  = (unsigned*)(ws + 16802304);
    unsigned* relBlo  = (unsigned*)(ws + 16802816);
    unsigned* relBhi  = (unsigned*)(ws + 16803328);
    short* h0S   = (short*)(ws + 16803840);         // 256 x 131,072 B
    short* h1S   = (short*)(ws + 50358272);         // 257 x 131,072 B
    // total ws usage: 84,043,776 B

    conv_x<<<2048, 256, 0, stream>>>(x, xbf);
    precomp<<<256, 256, 0, stream>>>(Wih0, fcW, fcb, Mf, c0ws);
    zero_f<<<10, 256, 0, stream>>>((float*)(ws + 16793600), 2560);     // flags + rel
    zero_f<<<128, 256, 0, stream>>>((float*)(ws + 50358272), 32768);   // h1S slot 0

    persist<<<256, 512, 0, stream>>>(Wih0, Whh0, bih0, bhh0,
                                     Wih1, Whh1, bih1, bhh1,
                                     fcW, fcb, x, xbf,
                                     h0S, h1S, Mf, c0ws, outp,
                                     flagAlo, flagAhi, flagBlo, flagBhi,
                                     relAlo, relAhi, relBlo, relBhi);
}

// Round 16
// 3419.558 us; speedup vs baseline: 1.2913x; 1.2913x over previous
//
#include <hip/hip_runtime.h>

#define B_ 64
#define S_ 256
#define F_ 256
#define H_ 1024

typedef __attribute__((ext_vector_type(8))) short bf16x8;
typedef __attribute__((ext_vector_type(4))) float f32x4;
typedef unsigned long long u64;

#define MFMA(a, b, c) __builtin_amdgcn_mfma_f32_16x16x32_bf16(a, b, c, 0, 0, 0)
#define CBAR() asm volatile("" ::: "memory")

__device__ __forceinline__ float sig(float v) { return 1.0f / (1.0f + __expf(-v)); }
__device__ __forceinline__ float tanh_(float v) { return 1.0f - 2.0f / (__expf(2.0f * v) + 1.0f); }
__device__ __forceinline__ short bfr(float f) {  // fp32 -> bf16 RNE
    unsigned u = __float_as_uint(f);
    u += 0x7fffu + ((u >> 16) & 1u);
    return (short)(u >> 16);
}

// agent-scope write-through 4B store (visible at coherence point)
__device__ __forceinline__ void st4(short* base, size_t byteoff, unsigned v) {
    __hip_atomic_store((unsigned*)((char*)base + byteoff), v,
                       __ATOMIC_RELAXED, __HIP_MEMORY_SCOPE_AGENT);
}

// master-only: parallel poll of 32 counter lines
__device__ __forceinline__ void flag_wait_g(unsigned* lines, int lane31, unsigned tgt) {
    for (;;) {
        unsigned s = __hip_atomic_load(&lines[lane31 * 16], __ATOMIC_RELAXED,
                                       __HIP_MEMORY_SCOPE_AGENT);
        s += __shfl_xor(s, 1);
        s += __shfl_xor(s, 2);
        s += __shfl_xor(s, 4);
        s += __shfl_xor(s, 8);
        s += __shfl_xor(s, 16);
        if (s >= tgt) break;
        __builtin_amdgcn_s_sleep(1);
    }
    CBAR();
}

// non-master: single release-line poll
__device__ __forceinline__ void rel_wait(unsigned* f, unsigned tgt) {
    while (__hip_atomic_load(f, __ATOMIC_RELAXED, __HIP_MEMORY_SCOPE_AGENT) < tgt)
        __builtin_amdgcn_s_sleep(1);
    CBAR();
}

__device__ __forceinline__ void tok_spin(volatile unsigned* tk, unsigned v) {
    while (*tk < v) __builtin_amdgcn_s_sleep(1);
    CBAR();
}

// x pre-conversion into A-frag layout: [t][kf 8][m 4][lane 64][8]
__global__ __launch_bounds__(256) void conv_x(const float* __restrict__ x,
                                              short* __restrict__ xbf) {
    int tid = blockIdx.x * 256 + threadIdx.x;
    int lane = tid & 63;
    int m = (tid >> 6) & 3;
    int kf = (tid >> 8) & 7;
    int t = tid >> 11;
    int b = m * 16 + (lane & 15);
    int kb = kf * 32 + (lane >> 4) * 8;
    const float* src = x + ((size_t)b * S_ + t) * F_ + kb;
    float4 v0 = *(const float4*)src, v1 = *(const float4*)(src + 4);
    bf16x8 o;
    o[0] = bfr(v0.x); o[1] = bfr(v0.y); o[2] = bfr(v0.z); o[3] = bfr(v0.w);
    o[4] = bfr(v1.x); o[5] = bfr(v1.y); o[6] = bfr(v1.z); o[7] = bfr(v1.w);
    *(bf16x8*)(xbf + (size_t)tid * 8) = o;
}

__global__ void zero_f(float* __restrict__ p, int n) {
    int i = blockIdx.x * blockDim.x + threadIdx.x;
    if (i < n) p[i] = 0.0f;
}

// one-time: M = Wa * fcW into B-frag layout; c0 = Wa * fcb
__global__ __launch_bounds__(256) void precomp(const float* __restrict__ Wih0,
                                               const float* __restrict__ fcW,
                                               const float* __restrict__ fcb,
                                               short* __restrict__ Mf,
                                               float* __restrict__ c0ws) {
    __shared__ float WaL[16][256];
    const int nf = blockIdx.x, tid = threadIdx.x;
    #pragma unroll
    for (int r = 0; r < 16; ++r) {
        int rowp = nf * 16 + r;
        int up = rowp >> 2, gat = rowp & 3;
        WaL[r][tid] = Wih0[(size_t)(gat * H_ + up) * 512 + 256 + tid];
    }
    __syncthreads();
    f32x4 acc[16];
    #pragma unroll
    for (int r = 0; r < 16; ++r) acc[r] = (f32x4){0, 0, 0, 0};
    for (int c = 0; c < 256; ++c) {
        f32x4 wv = *(const f32x4*)&fcW[(size_t)c * 1024 + tid * 4];
        #pragma unroll
        for (int r = 0; r < 16; ++r) acc[r] += WaL[r][c] * wv;
    }
    #pragma unroll
    for (int r = 0; r < 16; ++r) {
        #pragma unroll
        for (int jj = 0; jj < 4; ++jj) {
            int h = tid * 4 + jj;
            int kf = h >> 5;
            int lane = r + ((h >> 3) & 3) * 16;
            int j = h & 7;
            Mf[((size_t)nf * 32 + kf) * 512 + lane * 8 + j] = bfr(acc[r][jj]);
        }
    }
    if (tid < 16) {
        float s = 0.0f;
        for (int c = 0; c < 256; ++c) s += WaL[tid][c] * fcb[c];
        c0ws[nf * 16 + tid] = s;
    }
}

#define GATES(v)                                                        \
    float x1 = __shfl_xor((v), 1), x2 = __shfl_xor((v), 2), x3 = __shfl_xor((v), 3); \
    float aL = g1 ? x1 : (v), aH = g1 ? x3 : x2;                        \
    float bL = g1 ? (v) : x1, bH = g1 ? x2 : x3;                        \
    float i_ = g2 ? aH : aL;                                            \
    float f_ = g2 ? bH : bL;                                            \
    float gc = g2 ? aL : aH;                                            \
    float o_ = g2 ? bL : bH;                                            \
    i_ = sig(i_); f_ = sig(f_); o_ = sig(o_); gc = tanh_(gc);

__global__ __launch_bounds__(512, 1) void persist(
    const float* __restrict__ Wih0, const float* __restrict__ Whh0,
    const float* __restrict__ bih0, const float* __restrict__ bhh0,
    const float* __restrict__ Wih1, const float* __restrict__ Whh1,
    const float* __restrict__ bih1, const float* __restrict__ bhh1,
    const float* __restrict__ fcW,  const float* __restrict__ fcb,
    const float* __restrict__ x,    const short* __restrict__ xbf,
    short* __restrict__ h0S, short* __restrict__ h1S,
    const short* __restrict__ Mf, const float* __restrict__ c0ws,
    float* __restrict__ outp,
    unsigned* __restrict__ flagA, unsigned* __restrict__ flagB,
    unsigned* __restrict__ relA,  unsigned* __restrict__ relB)
{
    __shared__ f32x4 redGA[2048];   // 32 KB  ga partials (8 waves x 4 m)
    __shared__ f32x4 redBv[2048];   // 32 KB  layer1 partials (hh from s1, ih from s4)
    __shared__ f32x4 redDv[2048];   // 32 KB  P-update partials
    __shared__ f32x4 fcF[256];      //  4 KB  fc partials
    __shared__ short ldsC[16384];   // 32 KB  fc weights (nf<64)
    __shared__ unsigned tokA, tokB;
    __shared__ unsigned cAcnt, cBcnt;
    const int tid = threadIdx.x, lane = tid & 63, w = tid >> 6;   // w 0..7
    const int nf = blockIdx.x;
    const int lane31 = lane & 31;
    unsigned* lineA = &flagA[(nf >> 3) * 16];
    unsigned* lineB = &flagB[(nf >> 3) * 16];
    unsigned* myRelA = &relA[(nf >> 5) * 16];
    unsigned* myRelB = &relB[(nf >> 5) * 16];
    const int rowp = nf * 16 + (lane & 15);
    const int up = rowp >> 2, g = rowp & 3;
    const int g1 = lane & 1, g2 = lane & 2;
    const f32x4 zero4 = {0, 0, 0, 0};
    const int chunkA = (nf >> 3) * 4 + w;         // (w<4)
    const int lsBase = ((nf & 7) >> 1) * 16;
    const int pb = (nf & 1) * 4 + ((lane & 15) >> 3) * 2;
    const int mfc = nf >> 4;
    const bool isMaster = (nf == 255);            // master off the fc set (fc = nf<64)

    if (tid == 0) { tokA = 0; tokB = 0; cAcnt = 0; cBcnt = 0; }

    // ---- prologue: weights -> registers (role-specialized) ----
    bf16x8 wA0, waQ, wH[8], wX[8];
    {
        int k = w * 32 + (lane >> 4) * 8;
        const float* src = Wih0 + (size_t)(g * H_ + up) * 512 + k;
        #pragma unroll
        for (int j = 0; j < 8; ++j) wA0[j] = bfr(src[j]);
    }
    {
        int k = 256 + w * 32 + (lane >> 4) * 8;
        const float* src = Wih0 + (size_t)(g * H_ + up) * 512 + k;
        #pragma unroll
        for (int j = 0; j < 8; ++j) waQ[j] = bfr(src[j]);
    }
    if (w < 4) {
        #pragma unroll
        for (int i = 0; i < 8; ++i) {
            int k = (w * 8 + i) * 32 + (lane >> 4) * 8;
            const float* sh = Whh0 + (size_t)(g * H_ + up) * 1024 + k;
            const float* sx = Wih1 + (size_t)(g * H_ + up) * 1024 + k;
            #pragma unroll
            for (int j = 0; j < 8; ++j) { wH[i][j] = bfr(sh[j]); wX[i][j] = bfr(sx[j]); }
        }
    } else {
        #pragma unroll
        for (int i = 0; i < 8; ++i) {
            int k = ((w - 4) * 8 + i) * 32 + (lane >> 4) * 8;
            const float* sh = Whh1 + (size_t)(g * H_ + up) * 1024 + k;
            #pragma unroll
            for (int j = 0; j < 8; ++j) wH[i][j] = bfr(sh[j]);
            wX[i] = *(const bf16x8*)(Mf + ((size_t)nf * 32 + (w - 4) * 8 + i) * 512 + lane * 8);
        }
    }
    const float bias0 = bih0[g * H_ + up] + bhh0[g * H_ + up];
    const float bias1 = bih1[g * H_ + up] + bhh1[g * H_ + up];
    const float c0l = c0ws[nf * 16 + (lane & 15)];
    float biasC = 0.0f;
    if (nf < 64) {
        int rowc = (nf & 15) * 16 + (lane & 15);
        biasC = fcb[rowc];
        #pragma unroll
        for (int i = 0; i < 4; ++i) {
            int kf = w * 4 + i;
            int k = kf * 32 + (lane >> 4) * 8;
            const float* src = fcW + (size_t)rowc * 1024 + k;
            short* d = ldsC + ((size_t)kf * 64 + lane) * 8;
            #pragma unroll
            for (int j = 0; j < 8; ++j) d[j] = bfr(src[j]);
        }
    }
    __syncthreads();

    float cs0[4] = {0, 0, 0, 0}, cs1[4] = {0, 0, 0, 0};
    float areg[4] = {0, 0, 0, 0}, P[4] = {0, 0, 0, 0};

    // ---- prologue A1(0): x/Q MFMAs; h0(-1)=0 ----
    f32x4 ga0, ga1, ga2, ga3, q0, q1, q2, q3;
    f32x4 qp0 = zero4, qp1 = zero4, qp2 = zero4, qp3 = zero4;
    {
        const short* p = xbf + (size_t)w * 2048 + lane * 8;
        bf16x8 a0 = *(const bf16x8*)(p);
        bf16x8 a1 = *(const bf16x8*)(p + 512);
        bf16x8 a2 = *(const bf16x8*)(p + 1024);
        bf16x8 a3 = *(const bf16x8*)(p + 1536);
        ga0 = MFMA(a0, wA0, zero4);  ga1 = MFMA(a1, wA0, zero4);
        ga2 = MFMA(a2, wA0, zero4);  ga3 = MFMA(a3, wA0, zero4);
        q0 = MFMA(a0, waQ, zero4);  q1 = MFMA(a1, waQ, zero4);
        q2 = MFMA(a2, waQ, zero4);  q3 = MFMA(a3, waQ, zero4);
    }

    for (int t = 0; t < S_; ++t) {
        const unsigned ut = (unsigned)t;
        short* h0w = h0S + (size_t)t * 65536;            // h0(t)
        const short* h1r = h1S + (size_t)t * 65536;      // h1(t-1)
        short* h1w = h1S + (size_t)(t + 1) * 65536;      // h1(t)

        // ===== s1: hopB + waves 4-7 merged hh + M pass over h1(t-1) =====
        if (w == 0) {
            if (t > 0) {
                if (isMaster) {
                    flag_wait_g(flagB, lane31, 256u * ut);
                    if (lane < 8)
                        __hip_atomic_store(&relB[lane * 16], ut,
                                           __ATOMIC_RELAXED, __HIP_MEMORY_SCOPE_AGENT);
                } else {
                    rel_wait(myRelB, ut);
                }
                if (lane == 0) *(volatile unsigned*)&tokB = ut;
                CBAR();
            }
        } else if (w >= 4 && t > 0) {
            tok_spin(&tokB, ut);
        }
        redGA[(w * 4 + 0) * 64 + lane] = ga0;
        redGA[(w * 4 + 1) * 64 + lane] = ga1;
        redGA[(w * 4 + 2) * 64 + lane] = ga2;
        redGA[(w * 4 + 3) * 64 + lane] = ga3;
        f32x4 m0 = zero4, m1 = zero4, m2 = zero4, m3 = zero4;
        if (w >= 4) {
            f32x4 b0 = zero4, b1 = zero4, b2 = zero4, b3 = zero4;
            #pragma unroll
            for (int i = 0; i < 8; ++i) {
                const short* p = h1r + (size_t)((w - 4) * 8 + i) * 2048 + lane * 8;
                bf16x8 a0 = *(const bf16x8*)(p);
                bf16x8 a1 = *(const bf16x8*)(p + 512);
                bf16x8 a2 = *(const bf16x8*)(p + 1024);
                bf16x8 a3 = *(const bf16x8*)(p + 1536);
                if (t > 1) {
                    m0 = MFMA(a0, wX[i], m0);
                    m1 = MFMA(a1, wX[i], m1);
                    m2 = MFMA(a2, wX[i], m2);
                    m3 = MFMA(a3, wX[i], m3);
                }
                b0 = MFMA(a0, wH[i], b0);
                b1 = MFMA(a1, wH[i], b1);
                b2 = MFMA(a2, wH[i], b2);
                b3 = MFMA(a3, wH[i], b3);
            }
            redBv[(w * 4 + 0) * 64 + lane] = b0;
            redBv[(w * 4 + 1) * 64 + lane] = b1;
            redBv[(w * 4 + 2) * 64 + lane] = b2;
            redBv[(w * 4 + 3) * 64 + lane] = b3;
        }
        if (t > 0) {
            f32x4 R0, R1, R2, R3;
            if (t == 1) { R0 = qp0; R1 = qp1; R2 = qp2; R3 = qp3; }
            else if (w >= 4) {
                R0 = 1.15f * qp0 + 0.2f * m0;
                R1 = 1.15f * qp1 + 0.2f * m1;
                R2 = 1.15f * qp2 + 0.2f * m2;
                R3 = 1.15f * qp3 + 0.2f * m3;
            } else {
                R0 = 1.15f * qp0; R1 = 1.15f * qp1; R2 = 1.15f * qp2; R3 = 1.15f * qp3;
            }
            redDv[(w * 4 + 0) * 64 + lane] = R0;
            redDv[(w * 4 + 1) * 64 + lane] = R1;
            redDv[(w * 4 + 2) * 64 + lane] = R2;
            redDv[(w * 4 + 3) * 64 + lane] = R3;
        }
        __syncthreads();

        // ===== s2: waves 0-3: P-update + A3 pointwise + h0 publish + EARLY ARRIVE;
        //           waves 4-7: fc partials (out t-1) =====
        if (w < 4) {
            if (t > 0) {
                f32x4 sD = redDv[(0 * 4 + w) * 64 + lane];
                #pragma unroll
                for (int k = 1; k < 8; ++k) sD += redDv[(k * 4 + w) * 64 + lane];
                #pragma unroll
                for (int r = 0; r < 4; ++r)
                    P[r] = (t == 1) ? sD[r]
                         : (sD[r] + 0.15f * P[r] + 0.2f * c0l) * (1.0f / 1.5f);
            }
            f32x4 s = redGA[(0 * 4 + w) * 64 + lane];
            #pragma unroll
            for (int k = 1; k < 8; ++k) s += redGA[(k * 4 + w) * 64 + lane];
            #pragma unroll
            for (int r = 0; r < 4; ++r) {
                float v = s[r] + bias0 + P[r];
                GATES(v)
                float cn = f_ * cs0[r] + i_ * gc;
                cs0[r] = cn;
                float hn = o_ * tanh_(cn);
                int hv = (int)(unsigned short)bfr(hn);
                int ot = __shfl_xor(hv, 4);
                unsigned p32 = (lane & 4) ? (unsigned)((ot & 0xffff) | (hv << 16))
                                          : (unsigned)((hv & 0xffff) | (ot << 16));
                if ((lane & 7) == 0) {
                    int b = w * 16 + (lane >> 4) * 4 + r;
                    int ls = lsBase + (b & 15);
                    st4(h0w, (size_t)chunkA * 1024 + (size_t)ls * 16 + pb * 2, p32);
                }
            }
            // early arrival: this wave's h0 stores are drained; 4th wave bumps lineA
            asm volatile("s_waitcnt vmcnt(0)" ::: "memory");
            if (lane == 0) {
                unsigned old = __hip_atomic_fetch_add(&cAcnt, 1u, __ATOMIC_RELAXED,
                                                      __HIP_MEMORY_SCOPE_WORKGROUP);
                if (old == 4u * ut + 3u)
                    __hip_atomic_fetch_add(lineA, 1u, __ATOMIC_RELAXED,
                                           __HIP_MEMORY_SCOPE_AGENT);
            }
        } else if (nf < 64 && t > 0) {
            const int j = w - 4;
            f32x4 f0 = zero4;
            #pragma unroll
            for (int i = 0; i < 8; ++i) {
                const int kf = j * 8 + i;
                const bf16x8 bw = *(const bf16x8*)(ldsC + ((size_t)kf * 64 + lane) * 8);
                bf16x8 a = *(const bf16x8*)(h1r + (size_t)kf * 2048 + (size_t)mfc * 512 + lane * 8);
                f0 = MFMA(a, bw, f0);
            }
            fcF[j * 64 + lane] = f0;
        }
        __syncthreads();

        // ===== s3: hopA; wave 4 blends out(t-1) in the shadow =====
        if (w == 0) {
            if (isMaster) {
                flag_wait_g(flagA, lane31, 256u * (ut + 1u));
                if (lane < 8)
                    __hip_atomic_store(&relA[lane * 16], ut + 1u,
                                       __ATOMIC_RELAXED, __HIP_MEMORY_SCOPE_AGENT);
            } else {
                rel_wait(myRelA, ut + 1u);
            }
            if (lane == 0) *(volatile unsigned*)&tokA = ut + 1u;
            CBAR();
        } else if (w < 4) {
            tok_spin(&tokA, ut + 1u);
        } else if (w == 4 && nf < 64 && t > 0) {
            f32x4 s = fcF[lane];
            s += fcF[64 + lane];
            s += fcF[128 + lane];
            s += fcF[192 + lane];
            const int c = (nf & 15) * 16 + (lane & 15);
            #pragma unroll
            for (int r = 0; r < 4; ++r) {
                float ov = s[r] + biasC;
                int b = mfc * 16 + (lane >> 4) * 4 + r;
                size_t xi = ((size_t)b * S_ + (t - 1)) * F_ + c;
                float xv = x[xi];
                float na = (t == 1) ? xv
                         : (1.15f * xv + 0.15f * areg[r] + 0.2f * ov) * (1.0f / 1.5f);
                areg[r] = na;
                outp[xi] = na;
            }
        }

        // ===== s4: waves 0-3 (gated tokA): merged ih + next-step Whh0 pass over h0(t) =====
        if (w < 4) {
            f32x4 b0 = zero4, b1 = zero4, b2 = zero4, b3 = zero4;
            ga0 = zero4; ga1 = zero4; ga2 = zero4; ga3 = zero4;
            #pragma unroll
            for (int i = 0; i < 8; ++i) {
                const short* p = h0w + (size_t)(w * 8 + i) * 2048 + lane * 8;
                bf16x8 a0 = *(const bf16x8*)(p);
                bf16x8 a1 = *(const bf16x8*)(p + 512);
                bf16x8 a2 = *(const bf16x8*)(p + 1024);
                bf16x8 a3 = *(const bf16x8*)(p + 1536);
                b0 = MFMA(a0, wX[i], b0);
                b1 = MFMA(a1, wX[i], b1);
                b2 = MFMA(a2, wX[i], b2);
                b3 = MFMA(a3, wX[i], b3);
                ga0 = MFMA(a0, wH[i], ga0);
                ga1 = MFMA(a1, wH[i], ga1);
                ga2 = MFMA(a2, wH[i], ga2);
                ga3 = MFMA(a3, wH[i], ga3);
            }
            redBv[(w * 4 + 0) * 64 + lane] = b0;
            redBv[(w * 4 + 1) * 64 + lane] = b1;
            redBv[(w * 4 + 2) * 64 + lane] = b2;
            redBv[(w * 4 + 3) * 64 + lane] = b3;
        }
        __syncthreads();

        // ===== s5: B epilogue (waves 0-3), publish h1(t) + EARLY ARRIVE =====
        if (w < 4) {
            f32x4 s = redBv[(0 * 4 + w) * 64 + lane];
            #pragma unroll
            for (int k = 1; k < 8; ++k) s += redBv[(k * 4 + w) * 64 + lane];
            #pragma unroll
            for (int r = 0; r < 4; ++r) {
                float v = s[r] + bias1;
                GATES(v)
                float cn = f_ * cs1[r] + i_ * gc;
                cs1[r] = cn;
                float hn = o_ * tanh_(cn);
                int hv = (int)(unsigned short)bfr(hn);
                int ot = __shfl_xor(hv, 4);
                unsigned p32 = (lane & 4) ? (unsigned)((ot & 0xffff) | (hv << 16))
                                          : (unsigned)((hv & 0xffff) | (ot << 16));
                if ((lane & 7) == 0) {
                    int b = w * 16 + (lane >> 4) * 4 + r;
                    int ls = lsBase + (b & 15);
                    st4(h1w, (size_t)chunkA * 1024 + (size_t)ls * 16 + pb * 2, p32);
                }
            }
            asm volatile("s_waitcnt vmcnt(0)" ::: "memory");
            if (lane == 0) {
                unsigned old = __hip_atomic_fetch_add(&cBcnt, 1u, __ATOMIC_RELAXED,
                                                      __HIP_MEMORY_SCOPE_WORKGROUP);
                if (old == 4u * ut + 3u)
                    __hip_atomic_fetch_add(lineB, 1u, __ATOMIC_RELAXED,
                                           __HIP_MEMORY_SCOPE_AGENT);
            }
        }
        __syncthreads();

        // ===== s6: A1(t+1) x/Q (hopB filler) =====
        if (t < S_ - 1) {
            qp0 = q0; qp1 = q1; qp2 = q2; qp3 = q3;
            const short* p = xbf + (size_t)(t + 1) * 16384 + (size_t)w * 2048 + lane * 8;
            bf16x8 a0 = *(const bf16x8*)(p);
            bf16x8 a1 = *(const bf16x8*)(p + 512);
            bf16x8 a2 = *(const bf16x8*)(p + 1024);
            bf16x8 a3 = *(const bf16x8*)(p + 1536);
            ga0 = MFMA(a0, wA0, (w < 4) ? ga0 : zero4);
            ga1 = MFMA(a1, wA0, (w < 4) ? ga1 : zero4);
            ga2 = MFMA(a2, wA0, (w < 4) ? ga2 : zero4);
            ga3 = MFMA(a3, wA0, (w < 4) ? ga3 : zero4);
            q0 = MFMA(a0, waQ, zero4);  q1 = MFMA(a1, waQ, zero4);
            q2 = MFMA(a2, waQ, zero4);  q3 = MFMA(a3, waQ, zero4);
        }
    }

    // ===== tail: out(255) from h1(255) (slot 256) =====
    if (w == 0) {
        if (isMaster) {
            flag_wait_g(flagB, lane31, 256u * 256u);
            if (lane < 8)
                __hip_atomic_store(&relB[lane * 16], 256u,
                                   __ATOMIC_RELAXED, __HIP_MEMORY_SCOPE_AGENT);
        } else {
            rel_wait(myRelB, 256u);
        }
        if (lane == 0) *(volatile unsigned*)&tokB = 256u;
        CBAR();
    } else if (w >= 4) {
        tok_spin(&tokB, 256u);
    }
    if (nf < 64) {
        const short* h1f = h1S + (size_t)256 * 65536;
        if (w >= 4) {
            const int j = w - 4;
            f32x4 f0 = zero4;
            #pragma unroll
            for (int i = 0; i < 8; ++i) {
                const int kf = j * 8 + i;
                const bf16x8 bw = *(const bf16x8*)(ldsC + ((size_t)kf * 64 + lane) * 8);
                bf16x8 a = *(const bf16x8*)(h1f + (size_t)kf * 2048 + (size_t)mfc * 512 + lane * 8);
                f0 = MFMA(a, bw, f0);
            }
            fcF[j * 64 + lane] = f0;
        }
        __syncthreads();
        if (w == 4) {
            f32x4 s = fcF[lane];
            s += fcF[64 + lane];
            s += fcF[128 + lane];
            s += fcF[192 + lane];
            const int c = (nf & 15) * 16 + (lane & 15);
            #pragma unroll
            for (int r = 0; r < 4; ++r) {
                float ov = s[r] + biasC;
                int b = mfc * 16 + (lane >> 4) * 4 + r;
                size_t xi = ((size_t)b * S_ + (S_ - 1)) * F_ + c;
                float xv = x[xi];
                float na = (1.15f * xv + 0.15f * areg[r] + 0.2f * ov) * (1.0f / 1.5f);
                outp[xi] = na;
            }
        }
    }
}

extern "C" void kernel_launch(void* const* d_in, const int* in_sizes, int n_in,
                              void* d_out, int out_size, void* d_ws, size_t ws_size,
                              hipStream_t stream) {
    const float* x    = (const float*)d_in[0];
    const float* Wih0 = (const float*)d_in[1];
    const float* Whh0 = (const float*)d_in[2];
    const float* bih0 = (const float*)d_in[3];
    const float* bhh0 = (const float*)d_in[4];
    const float* Wih1 = (const float*)d_in[5];
    const float* Whh1 = (const float*)d_in[6];
    const float* bih1 = (const float*)d_in[7];
    const float* bhh1 = (const float*)d_in[8];
    const float* fcW  = (const float*)d_in[9];
    const float* fcb  = (const float*)d_in[10];
    float* outp = (float*)d_out;

    char* ws = (char*)d_ws;
    short* xbf   = (short*)(ws + 0);                // 8,388,608 B
    short* Mf    = (short*)(ws + 8388608);          // 8,388,608 B
    float* c0ws  = (float*)(ws + 16777216);         //    16,384 B
    unsigned* flagA = (unsigned*)(ws + 16793600);   //     2,048 B (32 lines)
    unsigned* flagB = (unsigned*)(ws + 16795648);   //     2,048 B (32 lines)
    unsigned* relA  = (unsigned*)(ws + 16797696);   //       512 B (8 lines)
    unsigned* relB  = (unsigned*)(ws + 16798208);   //       512 B (8 lines)
    short* h0S   = (short*)(ws + 16798720);         // 256 x 131,072 B
    short* h1S   = (short*)(ws + 50353152);         // 257 x 131,072 B
    // total ws usage: 84,038,656 B

    conv_x<<<2048, 256, 0, stream>>>(x, xbf);
    precomp<<<256, 256, 0, stream>>>(Wih0, fcW, fcb, Mf, c0ws);
    zero_f<<<5, 256, 0, stream>>>((float*)(ws + 16793600), 1280);      // flags + rel
    zero_f<<<128, 256, 0, stream>>>((float*)(ws + 50353152), 32768);   // h1S slot 0

    persist<<<256, 512, 0, stream>>>(Wih0, Whh0, bih0, bhh0,
                                     Wih1, Whh1, bih1, bhh1,
                                     fcW, fcb, x, xbf,
                                     h0S, h1S, Mf, c0ws, outp,
                                     flagA, flagB, relA, relB);
}

// Round 17
// 3295.627 us; speedup vs baseline: 1.3399x; 1.0376x over previous
//
#include <hip/hip_runtime.h>

#define B_ 64
#define S_ 256
#define F_ 256
#define H_ 1024

typedef __attribute__((ext_vector_type(8))) short bf16x8;
typedef __attribute__((ext_vector_type(4))) float f32x4;
typedef unsigned long long u64;

#define MFMA(a, b, c) __builtin_amdgcn_mfma_f32_16x16x32_bf16(a, b, c, 0, 0, 0)
#define CBAR() asm volatile("" ::: "memory")

__device__ __forceinline__ float sig(float v) { return 1.0f / (1.0f + __expf(-v)); }
__device__ __forceinline__ float tanh_(float v) { return 1.0f - 2.0f / (__expf(2.0f * v) + 1.0f); }
__device__ __forceinline__ short bfr(float f) {  // fp32 -> bf16 RNE
    unsigned u = __float_as_uint(f);
    u += 0x7fffu + ((u >> 16) & 1u);
    return (short)(u >> 16);
}

// agent-scope write-through 4B store (visible at coherence point)
__device__ __forceinline__ void st4(short* base, size_t byteoff, unsigned v) {
    __hip_atomic_store((unsigned*)((char*)base + byteoff), v,
                       __ATOMIC_RELAXED, __HIP_MEMORY_SCOPE_AGENT);
}

__device__ __forceinline__ void flag_add(unsigned* line) {
    asm volatile("s_waitcnt vmcnt(0)" ::: "memory");
    __hip_atomic_fetch_add(line, 1u, __ATOMIC_RELAXED, __HIP_MEMORY_SCOPE_AGENT);
}

// master-only: parallel poll of 32 counter lines
__device__ __forceinline__ void flag_wait_g(unsigned* lines, int lane31, unsigned tgt) {
    for (;;) {
        unsigned s = __hip_atomic_load(&lines[lane31 * 16], __ATOMIC_RELAXED,
                                       __HIP_MEMORY_SCOPE_AGENT);
        s += __shfl_xor(s, 1);
        s += __shfl_xor(s, 2);
        s += __shfl_xor(s, 4);
        s += __shfl_xor(s, 8);
        s += __shfl_xor(s, 16);
        if (s >= tgt) break;
        __builtin_amdgcn_s_sleep(1);
    }
    CBAR();
}

// consumer: single release-line poll (uniform address, one request/wave/round)
__device__ __forceinline__ void rel_wait(unsigned* f, unsigned tgt) {
    while (__hip_atomic_load(f, __ATOMIC_RELAXED, __HIP_MEMORY_SCOPE_AGENT) < tgt)
        __builtin_amdgcn_s_sleep(1);
    CBAR();
}

// x pre-conversion into A-frag layout: [t][kf 8][m 4][lane 64][8]
__global__ __launch_bounds__(256) void conv_x(const float* __restrict__ x,
                                              short* __restrict__ xbf) {
    int tid = blockIdx.x * 256 + threadIdx.x;
    int lane = tid & 63;
    int m = (tid >> 6) & 3;
    int kf = (tid >> 8) & 7;
    int t = tid >> 11;
    int b = m * 16 + (lane & 15);
    int kb = kf * 32 + (lane >> 4) * 8;
    const float* src = x + ((size_t)b * S_ + t) * F_ + kb;
    float4 v0 = *(const float4*)src, v1 = *(const float4*)(src + 4);
    bf16x8 o;
    o[0] = bfr(v0.x); o[1] = bfr(v0.y); o[2] = bfr(v0.z); o[3] = bfr(v0.w);
    o[4] = bfr(v1.x); o[5] = bfr(v1.y); o[6] = bfr(v1.z); o[7] = bfr(v1.w);
    *(bf16x8*)(xbf + (size_t)tid * 8) = o;
}

__global__ void zero_f(float* __restrict__ p, int n) {
    int i = blockIdx.x * blockDim.x + threadIdx.x;
    if (i < n) p[i] = 0.0f;
}

// one-time: M = Wa * fcW into B-frag layout; c0 = Wa * fcb
__global__ __launch_bounds__(256) void precomp(const float* __restrict__ Wih0,
                                               const float* __restrict__ fcW,
                                               const float* __restrict__ fcb,
                                               short* __restrict__ Mf,
                                               float* __restrict__ c0ws) {
    __shared__ float WaL[16][256];
    const int nf = blockIdx.x, tid = threadIdx.x;
    #pragma unroll
    for (int r = 0; r < 16; ++r) {
        int rowp = nf * 16 + r;
        int up = rowp >> 2, gat = rowp & 3;
        WaL[r][tid] = Wih0[(size_t)(gat * H_ + up) * 512 + 256 + tid];
    }
    __syncthreads();
    f32x4 acc[16];
    #pragma unroll
    for (int r = 0; r < 16; ++r) acc[r] = (f32x4){0, 0, 0, 0};
    for (int c = 0; c < 256; ++c) {
        f32x4 wv = *(const f32x4*)&fcW[(size_t)c * 1024 + tid * 4];
        #pragma unroll
        for (int r = 0; r < 16; ++r) acc[r] += WaL[r][c] * wv;
    }
    #pragma unroll
    for (int r = 0; r < 16; ++r) {
        #pragma unroll
        for (int jj = 0; jj < 4; ++jj) {
            int h = tid * 4 + jj;
            int kf = h >> 5;
            int lane = r + ((h >> 3) & 3) * 16;
            int j = h & 7;
            Mf[((size_t)nf * 32 + kf) * 512 + lane * 8 + j] = bfr(acc[r][jj]);
        }
    }
    if (tid < 16) {
        float s = 0.0f;
        for (int c = 0; c < 256; ++c) s += WaL[tid][c] * fcb[c];
        c0ws[nf * 16 + tid] = s;
    }
}

#define GATES(v)                                                        \
    float x1 = __shfl_xor((v), 1), x2 = __shfl_xor((v), 2), x3 = __shfl_xor((v), 3); \
    float aL = g1 ? x1 : (v), aH = g1 ? x3 : x2;                        \
    float bL = g1 ? (v) : x1, bH = g1 ? x2 : x3;                        \
    float i_ = g2 ? aH : aL;                                            \
    float f_ = g2 ? bH : bL;                                            \
    float gc = g2 ? aL : aH;                                            \
    float o_ = g2 ? bL : bH;                                            \
    i_ = sig(i_); f_ = sig(f_); o_ = sig(o_); gc = tanh_(gc);

__global__ __launch_bounds__(512, 1) void persist(
    const float* __restrict__ Wih0, const float* __restrict__ Whh0,
    const float* __restrict__ bih0, const float* __restrict__ bhh0,
    const float* __restrict__ Wih1, const float* __restrict__ Whh1,
    const float* __restrict__ bih1, const float* __restrict__ bhh1,
    const float* __restrict__ fcW,  const float* __restrict__ fcb,
    const float* __restrict__ x,    const short* __restrict__ xbf,
    short* __restrict__ h0S, short* __restrict__ h1S,
    const short* __restrict__ Mf, const float* __restrict__ c0ws,
    float* __restrict__ outp,
    unsigned* __restrict__ flagA, unsigned* __restrict__ flagB,
    unsigned* __restrict__ relA,  unsigned* __restrict__ relB)
{
    __shared__ f32x4 redGA[2048];   // 32 KB  ga partials (8 waves x 4 m)
    __shared__ f32x4 redBv[2048];   // 32 KB  layer1 partials (hh from s1, ih from s4)
    __shared__ f32x4 redDv[2048];   // 32 KB  P-update partials
    __shared__ f32x4 fcF[256];      //  4 KB  fc partials
    __shared__ short ldsC[16384];   // 32 KB  fc weights (nf<64)
    const int tid = threadIdx.x, lane = tid & 63, w = tid >> 6;   // w 0..7
    const int nf = blockIdx.x;
    const int lane31 = lane & 31;
    unsigned* lineA = &flagA[(nf >> 3) * 16];
    unsigned* lineB = &flagB[(nf >> 3) * 16];
    unsigned* myRelA = &relA[(nf >> 5) * 16];
    unsigned* myRelB = &relB[(nf >> 5) * 16];
    const int rowp = nf * 16 + (lane & 15);
    const int up = rowp >> 2, g = rowp & 3;
    const int g1 = lane & 1, g2 = lane & 2;
    const f32x4 zero4 = {0, 0, 0, 0};
    const int chunkA = (nf >> 3) * 4 + w;         // (w<4)
    const int lsBase = ((nf & 7) >> 1) * 16;
    const int pb = (nf & 1) * 4 + ((lane & 15) >> 3) * 2;
    const int mfc = nf >> 4;
    const bool isMaster = (nf == 255);            // master carries no fc duty (fc = nf<64)

    // ---- prologue: weights -> registers (role-specialized) ----
    bf16x8 wA0, waQ, wH[8], wX[8];
    {
        int k = w * 32 + (lane >> 4) * 8;
        const float* src = Wih0 + (size_t)(g * H_ + up) * 512 + k;
        #pragma unroll
        for (int j = 0; j < 8; ++j) wA0[j] = bfr(src[j]);
    }
    {
        int k = 256 + w * 32 + (lane >> 4) * 8;
        const float* src = Wih0 + (size_t)(g * H_ + up) * 512 + k;
        #pragma unroll
        for (int j = 0; j < 8; ++j) waQ[j] = bfr(src[j]);
    }
    if (w < 4) {
        #pragma unroll
        for (int i = 0; i < 8; ++i) {
            int k = (w * 8 + i) * 32 + (lane >> 4) * 8;
            const float* sh = Whh0 + (size_t)(g * H_ + up) * 1024 + k;
            const float* sx = Wih1 + (size_t)(g * H_ + up) * 1024 + k;
            #pragma unroll
            for (int j = 0; j < 8; ++j) { wH[i][j] = bfr(sh[j]); wX[i][j] = bfr(sx[j]); }
        }
    } else {
        #pragma unroll
        for (int i = 0; i < 8; ++i) {
            int k = ((w - 4) * 8 + i) * 32 + (lane >> 4) * 8;
            const float* sh = Whh1 + (size_t)(g * H_ + up) * 1024 + k;
            #pragma unroll
            for (int j = 0; j < 8; ++j) wH[i][j] = bfr(sh[j]);
            wX[i] = *(const bf16x8*)(Mf + ((size_t)nf * 32 + (w - 4) * 8 + i) * 512 + lane * 8);
        }
    }
    const float bias0 = bih0[g * H_ + up] + bhh0[g * H_ + up];
    const float bias1 = bih1[g * H_ + up] + bhh1[g * H_ + up];
    const float c0l = c0ws[nf * 16 + (lane & 15)];
    float biasC = 0.0f;
    if (nf < 64) {
        int rowc = (nf & 15) * 16 + (lane & 15);
        biasC = fcb[rowc];
        #pragma unroll
        for (int i = 0; i < 4; ++i) {
            int kf = w * 4 + i;
            int k = kf * 32 + (lane >> 4) * 8;
            const float* src = fcW + (size_t)rowc * 1024 + k;
            short* d = ldsC + ((size_t)kf * 64 + lane) * 8;
            #pragma unroll
            for (int j = 0; j < 8; ++j) d[j] = bfr(src[j]);
        }
    }
    __syncthreads();

    float cs0[4] = {0, 0, 0, 0}, cs1[4] = {0, 0, 0, 0};
    float areg[4] = {0, 0, 0, 0}, P[4] = {0, 0, 0, 0};

    // ---- prologue A1(0): x/Q MFMAs; h0(-1)=0 ----
    f32x4 ga0, ga1, ga2, ga3, q0, q1, q2, q3;
    f32x4 qp0 = zero4, qp1 = zero4, qp2 = zero4, qp3 = zero4;
    {
        const short* p = xbf + (size_t)w * 2048 + lane * 8;
        bf16x8 a0 = *(const bf16x8*)(p);
        bf16x8 a1 = *(const bf16x8*)(p + 512);
        bf16x8 a2 = *(const bf16x8*)(p + 1024);
        bf16x8 a3 = *(const bf16x8*)(p + 1536);
        ga0 = MFMA(a0, wA0, zero4);  ga1 = MFMA(a1, wA0, zero4);
        ga2 = MFMA(a2, wA0, zero4);  ga3 = MFMA(a3, wA0, zero4);
        q0 = MFMA(a0, waQ, zero4);  q1 = MFMA(a1, waQ, zero4);
        q2 = MFMA(a2, waQ, zero4);  q3 = MFMA(a3, waQ, zero4);
    }

    for (int t = 0; t < S_; ++t) {
        const unsigned ut = (unsigned)t;
        short* h0w = h0S + (size_t)t * 65536;            // h0(t)
        const short* h1r = h1S + (size_t)t * 65536;      // h1(t-1)
        short* h1w = h1S + (size_t)(t + 1) * 65536;      // h1(t)

        // ===== s1: hopB (master detect+release; consumers poll rel directly)
        //        + waves 4-7 merged hh + M pass over h1(t-1) =====
        if (t > 0) {
            if (w == 0 && isMaster) {
                flag_wait_g(flagB, lane31, 256u * ut);
                if (lane < 8)
                    __hip_atomic_store(&relB[lane * 16], ut,
                                       __ATOMIC_RELAXED, __HIP_MEMORY_SCOPE_AGENT);
            } else if (w >= 4) {
                rel_wait(myRelB, ut);
            }
        }
        redGA[(w * 4 + 0) * 64 + lane] = ga0;
        redGA[(w * 4 + 1) * 64 + lane] = ga1;
        redGA[(w * 4 + 2) * 64 + lane] = ga2;
        redGA[(w * 4 + 3) * 64 + lane] = ga3;
        f32x4 m0 = zero4, m1 = zero4, m2 = zero4, m3 = zero4;
        if (w >= 4) {
            f32x4 b0 = zero4, b1 = zero4, b2 = zero4, b3 = zero4;
            #pragma unroll
            for (int i = 0; i < 8; ++i) {
                const short* p = h1r + (size_t)((w - 4) * 8 + i) * 2048 + lane * 8;
                bf16x8 a0 = *(const bf16x8*)(p);
                bf16x8 a1 = *(const bf16x8*)(p + 512);
                bf16x8 a2 = *(const bf16x8*)(p + 1024);
                bf16x8 a3 = *(const bf16x8*)(p + 1536);
                if (t > 1) {
                    m0 = MFMA(a0, wX[i], m0);
                    m1 = MFMA(a1, wX[i], m1);
                    m2 = MFMA(a2, wX[i], m2);
                    m3 = MFMA(a3, wX[i], m3);
                }
                b0 = MFMA(a0, wH[i], b0);
                b1 = MFMA(a1, wH[i], b1);
                b2 = MFMA(a2, wH[i], b2);
                b3 = MFMA(a3, wH[i], b3);
            }
            redBv[(w * 4 + 0) * 64 + lane] = b0;
            redBv[(w * 4 + 1) * 64 + lane] = b1;
            redBv[(w * 4 + 2) * 64 + lane] = b2;
            redBv[(w * 4 + 3) * 64 + lane] = b3;
        }
        if (t > 0) {
            f32x4 R0, R1, R2, R3;
            if (t == 1) { R0 = qp0; R1 = qp1; R2 = qp2; R3 = qp3; }
            else if (w >= 4) {
                R0 = 1.15f * qp0 + 0.2f * m0;
                R1 = 1.15f * qp1 + 0.2f * m1;
                R2 = 1.15f * qp2 + 0.2f * m2;
                R3 = 1.15f * qp3 + 0.2f * m3;
            } else {
                R0 = 1.15f * qp0; R1 = 1.15f * qp1; R2 = 1.15f * qp2; R3 = 1.15f * qp3;
            }
            redDv[(w * 4 + 0) * 64 + lane] = R0;
            redDv[(w * 4 + 1) * 64 + lane] = R1;
            redDv[(w * 4 + 2) * 64 + lane] = R2;
            redDv[(w * 4 + 3) * 64 + lane] = R3;
        }
        __syncthreads();

        // ===== s2: waves 0-3: P-update + A3 pointwise + h0 publish;
        //           waves 4-7: fc partials (out t-1) =====
        if (w < 4) {
            if (t > 0) {
                f32x4 sD = redDv[(0 * 4 + w) * 64 + lane];
                #pragma unroll
                for (int k = 1; k < 8; ++k) sD += redDv[(k * 4 + w) * 64 + lane];
                #pragma unroll
                for (int r = 0; r < 4; ++r)
                    P[r] = (t == 1) ? sD[r]
                         : (sD[r] + 0.15f * P[r] + 0.2f * c0l) * (1.0f / 1.5f);
            }
            f32x4 s = redGA[(0 * 4 + w) * 64 + lane];
            #pragma unroll
            for (int k = 1; k < 8; ++k) s += redGA[(k * 4 + w) * 64 + lane];
            #pragma unroll
            for (int r = 0; r < 4; ++r) {
                float v = s[r] + bias0 + P[r];
                GATES(v)
                float cn = f_ * cs0[r] + i_ * gc;
                cs0[r] = cn;
                float hn = o_ * tanh_(cn);
                int hv = (int)(unsigned short)bfr(hn);
                int ot = __shfl_xor(hv, 4);
                unsigned p32 = (lane & 4) ? (unsigned)((ot & 0xffff) | (hv << 16))
                                          : (unsigned)((hv & 0xffff) | (ot << 16));
                if ((lane & 7) == 0) {
                    int b = w * 16 + (lane >> 4) * 4 + r;
                    int ls = lsBase + (b & 15);
                    st4(h0w, (size_t)chunkA * 1024 + (size_t)ls * 16 + pb * 2, p32);
                }
            }
        } else if (nf < 64 && t > 0) {
            const int j = w - 4;
            f32x4 f0 = zero4;
            #pragma unroll
            for (int i = 0; i < 8; ++i) {
                const int kf = j * 8 + i;
                const bf16x8 bw = *(const bf16x8*)(ldsC + ((size_t)kf * 64 + lane) * 8);
                bf16x8 a = *(const bf16x8*)(h1r + (size_t)kf * 2048 + (size_t)mfc * 512 + lane * 8);
                f0 = MFMA(a, bw, f0);
            }
            fcF[j * 64 + lane] = f0;
        }
        __syncthreads();                  // drains all waves' h0 stores
        if (tid == 0) flag_add(lineA);

        // ===== s3: hopA (master detect+release; waves 0-3 poll rel directly);
        //           wave 4 blends out(t-1) in the shadow =====
        if (w == 0) {
            if (isMaster) {
                flag_wait_g(flagA, lane31, 256u * (ut + 1u));
                if (lane < 8)
                    __hip_atomic_store(&relA[lane * 16], ut + 1u,
                                       __ATOMIC_RELAXED, __HIP_MEMORY_SCOPE_AGENT);
            } else {
                rel_wait(myRelA, ut + 1u);
            }
        } else if (w < 4) {
            rel_wait(myRelA, ut + 1u);
        } else if (w == 4 && nf < 64 && t > 0) {
            f32x4 s = fcF[lane];
            s += fcF[64 + lane];
            s += fcF[128 + lane];
            s += fcF[192 + lane];
            const int c = (nf & 15) * 16 + (lane & 15);
            #pragma unroll
            for (int r = 0; r < 4; ++r) {
                float ov = s[r] + biasC;
                int b = mfc * 16 + (lane >> 4) * 4 + r;
                size_t xi = ((size_t)b * S_ + (t - 1)) * F_ + c;
                float xv = x[xi];
                float na = (t == 1) ? xv
                         : (1.15f * xv + 0.15f * areg[r] + 0.2f * ov) * (1.0f / 1.5f);
                areg[r] = na;
                outp[xi] = na;
            }
        }

        // ===== s4: waves 0-3: merged ih + next-step Whh0 pass over h0(t) =====
        if (w < 4) {
            f32x4 b0 = zero4, b1 = zero4, b2 = zero4, b3 = zero4;
            ga0 = zero4; ga1 = zero4; ga2 = zero4; ga3 = zero4;
            #pragma unroll
            for (int i = 0; i < 8; ++i) {
                const short* p = h0w + (size_t)(w * 8 + i) * 2048 + lane * 8;
                bf16x8 a0 = *(const bf16x8*)(p);
                bf16x8 a1 = *(const bf16x8*)(p + 512);
                bf16x8 a2 = *(const bf16x8*)(p + 1024);
                bf16x8 a3 = *(const bf16x8*)(p + 1536);
                b0 = MFMA(a0, wX[i], b0);
                b1 = MFMA(a1, wX[i], b1);
                b2 = MFMA(a2, wX[i], b2);
                b3 = MFMA(a3, wX[i], b3);
                ga0 = MFMA(a0, wH[i], ga0);
                ga1 = MFMA(a1, wH[i], ga1);
                ga2 = MFMA(a2, wH[i], ga2);
                ga3 = MFMA(a3, wH[i], ga3);
            }
            redBv[(w * 4 + 0) * 64 + lane] = b0;
            redBv[(w * 4 + 1) * 64 + lane] = b1;
            redBv[(w * 4 + 2) * 64 + lane] = b2;
            redBv[(w * 4 + 3) * 64 + lane] = b3;
        }
        __syncthreads();

        // ===== s5: B epilogue (waves 0-3), publish h1(t) =====
        if (w < 4) {
            f32x4 s = redBv[(0 * 4 + w) * 64 + lane];
            #pragma unroll
            for (int k = 1; k < 8; ++k) s += redBv[(k * 4 + w) * 64 + lane];
            #pragma unroll
            for (int r = 0; r < 4; ++r) {
                float v = s[r] + bias1;
                GATES(v)
                float cn = f_ * cs1[r] + i_ * gc;
                cs1[r] = cn;
                float hn = o_ * tanh_(cn);
                int hv = (int)(unsigned short)bfr(hn);
                int ot = __shfl_xor(hv, 4);
                unsigned p32 = (lane & 4) ? (unsigned)((ot & 0xffff) | (hv << 16))
                                          : (unsigned)((hv & 0xffff) | (ot << 16));
                if ((lane & 7) == 0) {
                    int b = w * 16 + (lane >> 4) * 4 + r;
                    int ls = lsBase + (b & 15);
                    st4(h1w, (size_t)chunkA * 1024 + (size_t)ls * 16 + pb * 2, p32);
                }
            }
        }
        __syncthreads();                  // drains all waves' h1 stores
        if (tid == 0) flag_add(lineB);

        // ===== s6: A1(t+1) x/Q (hopB filler) =====
        if (t < S_ - 1) {
            qp0 = q0; qp1 = q1; qp2 = q2; qp3 = q3;
            const short* p = xbf + (size_t)(t + 1) * 16384 + (size_t)w * 2048 + lane * 8;
            bf16x8 a0 = *(const bf16x8*)(p);
            bf16x8 a1 = *(const bf16x8*)(p + 512);
            bf16x8 a2 = *(const bf16x8*)(p + 1024);
            bf16x8 a3 = *(const bf16x8*)(p + 1536);
            ga0 = MFMA(a0, wA0, (w < 4) ? ga0 : zero4);
            ga1 = MFMA(a1, wA0, (w < 4) ? ga1 : zero4);
            ga2 = MFMA(a2, wA0, (w < 4) ? ga2 : zero4);
            ga3 = MFMA(a3, wA0, (w < 4) ? ga3 : zero4);
            q0 = MFMA(a0, waQ, zero4);  q1 = MFMA(a1, waQ, zero4);
            q2 = MFMA(a2, waQ, zero4);  q3 = MFMA(a3, waQ, zero4);
        }
    }

    // ===== tail: out(255) from h1(255) (slot 256) =====
    if (w == 0 && isMaster) {
        flag_wait_g(flagB, lane31, 256u * 256u);
        if (lane < 8)
            __hip_atomic_store(&relB[lane * 16], 256u,
                               __ATOMIC_RELAXED, __HIP_MEMORY_SCOPE_AGENT);
    }
    if (nf < 64) {
        const short* h1f = h1S + (size_t)256 * 65536;
        if (w >= 4) {
            rel_wait(myRelB, 256u);
            const int j = w - 4;
            f32x4 f0 = zero4;
            #pragma unroll
            for (int i = 0; i < 8; ++i) {
                const int kf = j * 8 + i;
                const bf16x8 bw = *(const bf16x8*)(ldsC + ((size_t)kf * 64 + lane) * 8);
                bf16x8 a = *(const bf16x8*)(h1f + (size_t)kf * 2048 + (size_t)mfc * 512 + lane * 8);
                f0 = MFMA(a, bw, f0);
            }
            fcF[j * 64 + lane] = f0;
        }
        __syncthreads();
        if (w == 4) {
            f32x4 s = fcF[lane];
            s += fcF[64 + lane];
            s += fcF[128 + lane];
            s += fcF[192 + lane];
            const int c = (nf & 15) * 16 + (lane & 15);
            #pragma unroll
            for (int r = 0; r < 4; ++r) {
                float ov = s[r] + biasC;
                int b = mfc * 16 + (lane >> 4) * 4 + r;
                size_t xi = ((size_t)b * S_ + (S_ - 1)) * F_ + c;
                float xv = x[xi];
                float na = (1.15f * xv + 0.15f * areg[r] + 0.2f * ov) * (1.0f / 1.5f);
                outp[xi] = na;
            }
        }
    }
}

extern "C" void kernel_launch(void* const* d_in, const int* in_sizes, int n_in,
                              void* d_out, int out_size, void* d_ws, size_t ws_size,
                              hipStream_t stream) {
    const float* x    = (const float*)d_in[0];
    const float* Wih0 = (const float*)d_in[1];
    const float* Whh0 = (const float*)d_in[2];
    const float* bih0 = (const float*)d_in[3];
    const float* bhh0 = (const float*)d_in[4];
    const float* Wih1 = (const float*)d_in[5];
    const float* Whh1 = (const float*)d_in[6];
    const float* bih1 = (const float*)d_in[7];
    const float* bhh1 = (const float*)d_in[8];
    const float* fcW  = (const float*)d_in[9];
    const float* fcb  = (const float*)d_in[10];
    float* outp = (float*)d_out;

    char* ws = (char*)d_ws;
    short* xbf   = (short*)(ws + 0);                // 8,388,608 B
    short* Mf    = (short*)(ws + 8388608);          // 8,388,608 B
    float* c0ws  = (float*)(ws + 16777216);         //    16,384 B
    unsigned* flagA = (unsigned*)(ws + 16793600);   //     2,048 B (32 lines)
    unsigned* flagB = (unsigned*)(ws + 16795648);   //     2,048 B (32 lines)
    unsigned* relA  = (unsigned*)(ws + 16797696);   //       512 B (8 lines)
    unsigned* relB  = (unsigned*)(ws + 16798208);   //       512 B (8 lines)
    short* h0S   = (short*)(ws + 16798720);         // 256 x 131,072 B
    short* h1S   = (short*)(ws + 50353152);         // 257 x 131,072 B
    // total ws usage: 84,038,656 B

    conv_x<<<2048, 256, 0, stream>>>(x, xbf);
    precomp<<<256, 256, 0, stream>>>(Wih0, fcW, fcb, Mf, c0ws);
    zero_f<<<5, 256, 0, stream>>>((float*)(ws + 16793600), 1280);      // flags + rel
    zero_f<<<128, 256, 0, stream>>>((float*)(ws + 50353152), 32768);   // h1S slot 0

    persist<<<256, 512, 0, stream>>>(Wih0, Whh0, bih0, bhh0,
                                     Wih1, Whh1, bih1, bhh1,
                                     fcW, fcb, x, xbf,
                                     h0S, h1S, Mf, c0ws, outp,
                                     flagA, flagB, relA, relB);
}